// Round 1
// baseline (141.579 us; speedup 1.0000x reference)
//
#include <hip/hip_runtime.h>
#include <math.h>

// Problem constants (fixed by reference): B=16, K=64, H=96, W=96
#define NB 16
#define NK 64
#define NH 96
#define NW 96
#define HW (NH * NW)          // 9216
#define PAIRS (NB * NK)       // 1024 maps per stack
#define HW4 (HW / 4)          // 2304 float4 per map
#define MAP_ELEMS ((size_t)NB * NK * HW)   // 9437184

// Output layout (flat, return order):
//   Dk           @ 0
//   tf_Dk        @ MAP_ELEMS
//   keypoint     @ 2*MAP_ELEMS                 ([B, 3K, 2] = 6144)
//   tf_keypoint  @ 2*MAP_ELEMS + 6144
//   get_zeta     @ 2*MAP_ELEMS + 12288         ([B, K] = 1024)
//   tf_get_zeta  @ 2*MAP_ELEMS + 13312
#define KP_BASE   ((size_t)2 * MAP_ELEMS)
#define KP_STACK  ((size_t)NB * 3 * NK * 2)    // 6144
#define ZETA_BASE (KP_BASE + 2 * KP_STACK)

__device__ __forceinline__ float sigf(float x) {
    return 1.0f / (1.0f + expf(-x));
}

// Stage 1: per (stack, b, k) map — sigmoid + write Dk, block-reduce
// zeta / sum(s*x) / sum(s*y) in double. One block per map.
__global__ __launch_bounds__(256) void stage1(
        const float* __restrict__ Rk,
        const float* __restrict__ tfRk,
        float* __restrict__ out,
        double* __restrict__ ws3) {
    const int blk   = blockIdx.x;
    const int stack = blk >> 10;      // 0: Rk, 1: tf_Rk
    const int pair  = blk & 1023;     // b*64 + k

    const float4* __restrict__ s4 =
        (const float4*)((stack ? tfRk : Rk) + (size_t)pair * HW);
    float4* __restrict__ d4 =
        (float4*)(out + (size_t)stack * MAP_ELEMS + (size_t)pair * HW);

    const int t = threadIdx.x;
    double zeta = 0.0, kx = 0.0, ky = 0.0;

    #pragma unroll
    for (int i = 0; i < HW4 / 256; ++i) {   // 9 iters
        const int idx = t + i * 256;
        float4 v = s4[idx];
        float4 s;
        s.x = sigf(v.x); s.y = sigf(v.y); s.z = sigf(v.z); s.w = sigf(v.w);
        d4[idx] = s;
        const int fx = idx * 4;           // flat element index
        const int x0 = fx % NW;           // float4 never crosses a row (96%4==0)
        const int y  = fx / NW;
        const double sum4 = (double)s.x + (double)s.y + (double)s.z + (double)s.w;
        zeta += sum4;
        kx   += sum4 * (double)x0 + ((double)s.y + 2.0 * (double)s.z + 3.0 * (double)s.w);
        ky   += sum4 * (double)y;
    }

    // wave (64-lane) shuffle reduce, then cross-wave via LDS
    for (int o = 32; o > 0; o >>= 1) {
        zeta += __shfl_down(zeta, o, 64);
        kx   += __shfl_down(kx,   o, 64);
        ky   += __shfl_down(ky,   o, 64);
    }
    __shared__ double sh[3][4];
    const int lane = t & 63, wave = t >> 6;
    if (lane == 0) { sh[0][wave] = zeta; sh[1][wave] = kx; sh[2][wave] = ky; }
    __syncthreads();
    if (t == 0) {
        const double z  = sh[0][0] + sh[0][1] + sh[0][2] + sh[0][3];
        const double xx = sh[1][0] + sh[1][1] + sh[1][2] + sh[1][3];
        const double yy = sh[2][0] + sh[2][1] + sh[2][2] + sh[2][3];
        const int gid = stack * PAIRS + pair;
        ws3[gid * 3 + 0] = z;
        ws3[gid * 3 + 1] = xx;
        ws3[gid * 3 + 2] = yy;
        out[ZETA_BASE + (size_t)stack * PAIRS + pair] = (float)z;
    }
}

// Stage 2: decode keypoints. One thread per (stack, b, k).
__global__ __launch_bounds__(256) void stage2(
        const float* __restrict__ Rk,
        const float* __restrict__ tfRk,
        float* __restrict__ out,
        const double* __restrict__ ws3) {
#pragma clang fp contract(off)
    const int gid = blockIdx.x * blockDim.x + threadIdx.x;
    if (gid >= 2 * PAIRS) return;
    const int stack = gid >> 10;
    const int pair  = gid & 1023;
    const int b = pair >> 6, k = pair & 63;

    const double z  = ws3[gid * 3 + 0];
    const double kx = ws3[gid * 3 + 1];
    const double ky = ws3[gid * 3 + 2];

    // mimic reference: fp32 division of the (near-exact) sums, round half-even
    const float zf  = (float)z;
    const float kpx = rintf((float)kx / zf);
    const float kpy = rintf((float)ky / zf);

    const int wi = (int)kpx;
    const int hi = (int)kpy;
    const float* src = (stack ? tfRk : Rk) + (size_t)pair * HW;
    const float d = sigf(src[hi * NW + wi]);

    const float tx = kpx * d;            // no fma contraction (pragma above)
    const float ty = kpy * d;
    const float k1x = truncf(kpx + tx), k1y = truncf(kpy + ty);
    const float k2x = truncf(kpx - tx), k2y = truncf(kpy - ty);

    float* kp = out + KP_BASE + (size_t)stack * KP_STACK + (size_t)b * (3 * NK * 2);
    kp[k * 2 + 0]            = kpx;  kp[k * 2 + 1]            = kpy;
    kp[(NK + k) * 2 + 0]     = k1x;  kp[(NK + k) * 2 + 1]     = k1y;
    kp[(2 * NK + k) * 2 + 0] = k2x;  kp[(2 * NK + k) * 2 + 1] = k2y;
}

extern "C" void kernel_launch(void* const* d_in, const int* in_sizes, int n_in,
                              void* d_out, int out_size, void* d_ws, size_t ws_size,
                              hipStream_t stream) {
    const float* Rk   = (const float*)d_in[0];
    const float* tfRk = (const float*)d_in[1];
    float* out   = (float*)d_out;
    double* ws3  = (double*)d_ws;   // 2048 * 3 doubles = 48 KB

    stage1<<<2 * PAIRS, 256, 0, stream>>>(Rk, tfRk, out, ws3);
    stage2<<<(2 * PAIRS + 255) / 256, 256, 0, stream>>>(Rk, tfRk, out, ws3);
}